// Round 15
// baseline (102.516 us; speedup 1.0000x reference)
//
#include <hip/hip_runtime.h>
#include <stdint.h>

#define B_ 32
#define N_ 1024
#define D_ 512
#define G_ 32

typedef __attribute__((ext_vector_type(8))) short short8;
typedef __attribute__((ext_vector_type(4))) float f32x4;
union U4S8 { uint4 u; short8 s; };

// ws float-offsets:
//   [0, 2097152)   : partials, 256 blocks x [32 g][256 o] u32(lo=bf16 m1, hi=bf16 m2) = 8 MB
//   WS_DN (+8192)  : denom partials, 256 x 32
//   WS_WF (+8192)  : W bf16 frag-layout (2048 uint4 = 32 KB)
//   WS_CNT (+32)   : per-b completion counters (u32), zeroed by K0 each call
#define WS_DN  2097152
#define WS_WF  2105344
#define WS_CNT 2113536

__device__ inline uint32_t pack_bf16x2(float a, float b) {
  uint32_t ua = __float_as_uint(a);
  uint32_t ub = __float_as_uint(b);
  ua += 0x7FFFu + ((ua >> 16) & 1u);
  ub += 0x7FFFu + ((ub >> 16) & 1u);
  return (ua >> 16) | (ub & 0xFFFF0000u);
}
__device__ inline uint16_t bf16r(float a) {
  uint32_t u = __float_as_uint(a);
  u += 0x7FFFu + ((u >> 16) & 1u);
  return (uint16_t)(u >> 16);
}
__device__ inline float bflo(uint32_t u) { return __uint_as_float(u << 16); }
__device__ inline float bfhi(uint32_t u) { return __uint_as_float(u & 0xFFFF0000u); }
__device__ inline int slot_of(int o) { return (o & 7) ^ ((o >> 3) & 3); }

// ---------------- K0: pre-pack W + zero completion counters -----------------
__global__ __launch_bounds__(256) void mdn_k0(
    const float* __restrict__ W, float* ws)
{
  int s = blockIdx.x * 256 + threadIdx.x;     // 0..2047
  if (blockIdx.x == 0 && threadIdx.x < 32)
    ((uint32_t*)(ws + WS_CNT))[threadIdx.x] = 0u;
  int g = s >> 6;
  int d0 = (s & 63) * 8;
  const float4* src = (const float4*)(W + g * D_ + d0);
  float4 f0 = src[0], f1 = src[1];
  int ks = d0 >> 5, ksub = (d0 >> 3) & 3;
  uint4 v;
  v.x = pack_bf16x2(f0.x, f0.y); v.y = pack_bf16x2(f0.z, f0.w);
  v.z = pack_bf16x2(f1.x, f1.y); v.w = pack_bf16x2(f1.z, f1.w);
  ((uint4*)(ws + WS_WF))[(ks * 4 + ksub) * 32 + g] = v;
}

// ---------------- KF: single-x-pass fused kernel + in-kernel finalize -------
// 256 blocks x 512 thr (8 waves x 16 rows = 128 rows), 1 block/CU.
// Phase 1: x direct-to-reg (read ONCE); logits MFMA vs prepacked W; packed
//   A-frag u32s written LINEARLY to XT[oc][r][16 oi] (one b128/k-step).
// Phase 2: moments MFMA; B-frags via ds_read_b64_tr_b16; partials packed
//   u32(lo=bf16 m1, hi=bf16 m2).
// Tail: decoupled-lookback — __threadfence(); atomicAdd(cnt[b]); the 8th
//   arriver reduces the 8 chunk partials (fixed order, deterministic) and
//   writes final weights/scales/locs. No K3 kernel.
__global__ __launch_bounds__(512, 2) void mdn_kf(
    const float* __restrict__ x, const float* __restrict__ bpi, float* ws,
    float* __restrict__ out)
{
  __shared__ uint32_t XT[32768];     // 128 KB: [32 oc][128 r][16 oi] bf16 linear
  __shared__ uint32_t PT[2048];      //   8 KB: piT [32 g][128 r bf16], swizzled
  __shared__ float wpart[8][32];
  __shared__ int lastflag;
  __shared__ float dnm[G_];

  const int t = threadIdx.x;
  const int bid = blockIdx.x;
  const int b = bid >> 3;
  const int n0 = (bid & 7) * 128;
  const int w = t >> 6;
  const int lane = t & 63;
  const int l15 = lane & 15, l4 = lane >> 4;

  // ---------------- Phase 1: logits + linear subtiled staging ----------------
  const float* abase =
      x + ((size_t)(b * N_ + n0 + w * 16 + l15)) * D_ + l4 * 8;
  const uint4* wf4 = (const uint4*)(ws + WS_WF);
  const int r = w * 16 + l15;        // this thread's row (0..127)

  f32x4 acc0 = {0.f, 0.f, 0.f, 0.f};
  f32x4 acc1 = {0.f, 0.f, 0.f, 0.f};

  #pragma unroll
  for (int h = 0; h < 2; ++h) {
    float4 fa[8], fb[8];
    #pragma unroll
    for (int k = 0; k < 8; ++k) {
      const float* s = abase + (h * 8 + k) * 32;
      fa[k] = *(const float4*)s; fb[k] = *(const float4*)(s + 4);
    }
    #pragma unroll
    for (int k = 0; k < 8; ++k) {
      int ks = h * 8 + k;
      U4S8 a;
      a.u.x = pack_bf16x2(fa[k].x, fa[k].y);
      a.u.y = pack_bf16x2(fa[k].z, fa[k].w);
      a.u.z = pack_bf16x2(fb[k].x, fb[k].y);
      a.u.w = pack_bf16x2(fb[k].z, fb[k].w);
      // linear subtiled store: d0 = l4*8 + ks*32; oc = d0>>4; oi = d0&15
      {
        int d0 = l4 * 8 + ks * 32;
        unsigned xtb = (unsigned)((d0 >> 4) * 4096 + r * 32 + (d0 & 15) * 2);
        *(uint4*)((char*)XT + xtb) = a.u;      // 16B aligned
      }
      // logits MFMA
      int wi = (ks * 4 + l4) * 32 + l15;
      U4S8 w0, w1;
      w0.u = wf4[wi];
      w1.u = wf4[wi + 16];
      acc0 = __builtin_amdgcn_mfma_f32_16x16x32_bf16(a.s, w0.s, acc0, 0, 0, 0);
      acc1 = __builtin_amdgcn_mfma_f32_16x16x32_bf16(a.s, w1.s, acc1, 0, 0, 0);
    }
  }

  // bias + in-register softmax (C layout: g = l15 / 16+l15; row = w*16+l4*4+j)
  float bs0 = bpi[l15], bs1 = bpi[16 + l15];
  float pi0[4], pi1[4];
  float dsum0 = 0.f, dsum1 = 0.f;
  #pragma unroll
  for (int j = 0; j < 4; ++j) {
    float v0 = acc0[j] + bs0, v1 = acc1[j] + bs1;
    float m = fmaxf(v0, v1);
    m = fmaxf(m, __shfl_xor(m, 1));
    m = fmaxf(m, __shfl_xor(m, 2));
    m = fmaxf(m, __shfl_xor(m, 4));
    m = fmaxf(m, __shfl_xor(m, 8));
    float e0 = __expf(v0 - m), e1 = __expf(v1 - m);
    float s = e0 + e1;
    s += __shfl_xor(s, 1); s += __shfl_xor(s, 2);
    s += __shfl_xor(s, 4); s += __shfl_xor(s, 8);
    float inv = 1.0f / s;
    pi0[j] = e0 * inv; pi1[j] = e1 * inv;
    dsum0 += pi0[j];   dsum1 += pi1[j];
  }
  dsum0 += __shfl_xor(dsum0, 16); dsum0 += __shfl_xor(dsum0, 32);
  dsum1 += __shfl_xor(dsum1, 16); dsum1 += __shfl_xor(dsum1, 32);
  if (lane < 16) { wpart[w][lane] = dsum0; wpart[w][16 + lane] = dsum1; }

  // piT -> LDS (u16 scatter, swizzled; only 8 per thread)
  {
    uint16_t* p16 = (uint16_t*)PT;
    int rbase = w * 16 + l4 * 4;
    int g0 = l15, g1 = 16 + l15;
    int s0 = slot_of(g0) << 3, s1 = slot_of(g1) << 3;
    #pragma unroll
    for (int j = 0; j < 4; ++j) {
      int rr = rbase + j;
      p16[g0 * 128 + (rr ^ s0)] = bf16r(pi0[j]);
      p16[g1 * 128 + (rr ^ s1)] = bf16r(pi1[j]);
    }
  }
  __syncthreads();

  if (t < 32) {
    float s = 0.f;
    #pragma unroll
    for (int ww = 0; ww < 8; ++ww) s += wpart[ww][t];
    ws[WS_DN + (size_t)bid * 32 + t] = s;
  }

  // ---------------- Phase 2: moments via HW transpose reads ----------------
  f32x4 m1a[2][2] = {{{0.f,0.f,0.f,0.f},{0.f,0.f,0.f,0.f}},
                     {{0.f,0.f,0.f,0.f},{0.f,0.f,0.f,0.f}}};
  f32x4 m2a[2][2] = {{{0.f,0.f,0.f,0.f},{0.f,0.f,0.f,0.f}},
                     {{0.f,0.f,0.f,0.f},{0.f,0.f,0.f,0.f}}};
  const int gA0 = l15, gA1 = 16 + l15;
  const int sA0 = slot_of(gA0) << 2, sA1 = slot_of(gA1) << 2;
  const unsigned xtb0 = (unsigned)(uintptr_t)XT;

  #pragma unroll
  for (int ksi = 0; ksi < 4; ++ksi) {
    int rofs = ksi * 16 + l4 * 4;            // u32 offset within a PT row
    U4S8 a0, a1;
    a0.u = *(const uint4*)(PT + gA0 * 64 + (rofs ^ sA0));
    a1.u = *(const uint4*)(PT + gA1 * 64 + (rofs ^ sA1));
    // per-lane tr_read addr: tile (rows ksi*32+l4*8 ..+3) + column l15
    const unsigned rowb = (unsigned)(ksi * 1024 + l4 * 256 + l15 * 8);
    #pragma unroll
    for (int ot = 0; ot < 2; ++ot) {
      unsigned am = xtb0 + (unsigned)((w * 2 + ot) * 4096) + rowb;
      unsigned as = am + 16 * 4096;
      uint64_t q0, q1, q2, q3;
      asm volatile("ds_read_b64_tr_b16 %0, %1" : "=v"(q0) : "v"(am));
      asm volatile("ds_read_b64_tr_b16 %0, %1 offset:128" : "=v"(q1) : "v"(am));
      asm volatile("ds_read_b64_tr_b16 %0, %1" : "=v"(q2) : "v"(as));
      asm volatile("ds_read_b64_tr_b16 %0, %1 offset:128" : "=v"(q3) : "v"(as));
      asm volatile("s_waitcnt lgkmcnt(0)" ::: "memory");
      __builtin_amdgcn_sched_barrier(0);
      U4S8 Bm, Bs;
      Bm.u.x = (uint32_t)q0; Bm.u.y = (uint32_t)(q0 >> 32);
      Bm.u.z = (uint32_t)q1; Bm.u.w = (uint32_t)(q1 >> 32);
      Bs.u.x = (uint32_t)q2; Bs.u.y = (uint32_t)(q2 >> 32);
      Bs.u.z = (uint32_t)q3; Bs.u.w = (uint32_t)(q3 >> 32);
      uint32_t bm[4] = {Bm.u.x, Bm.u.y, Bm.u.z, Bm.u.w};
      uint32_t sw[4] = {Bs.u.x, Bs.u.y, Bs.u.z, Bs.u.w};
      U4S8 B2;
      uint32_t b2w[4];
      #pragma unroll
      for (int i = 0; i < 4; ++i) {
        float lo = bflo(bm[i]) * bflo(bm[i]) + bflo(sw[i]) * bflo(sw[i]);
        float hi = bfhi(bm[i]) * bfhi(bm[i]) + bfhi(sw[i]) * bfhi(sw[i]);
        b2w[i] = pack_bf16x2(lo, hi);
      }
      B2.u.x = b2w[0]; B2.u.y = b2w[1]; B2.u.z = b2w[2]; B2.u.w = b2w[3];
      m1a[0][ot] = __builtin_amdgcn_mfma_f32_16x16x32_bf16(a0.s, Bm.s, m1a[0][ot], 0, 0, 0);
      m1a[1][ot] = __builtin_amdgcn_mfma_f32_16x16x32_bf16(a1.s, Bm.s, m1a[1][ot], 0, 0, 0);
      m2a[0][ot] = __builtin_amdgcn_mfma_f32_16x16x32_bf16(a0.s, B2.s, m2a[0][ot], 0, 0, 0);
      m2a[1][ot] = __builtin_amdgcn_mfma_f32_16x16x32_bf16(a1.s, B2.s, m2a[1][ot], 0, 0, 0);
    }
  }

  // partial store: [32 g][256 o] u32 (lo = bf16 m1, hi = bf16 m2)
  uint32_t* dst = (uint32_t*)ws + (size_t)bid * 8192;
  #pragma unroll
  for (int gt = 0; gt < 2; ++gt) {
    #pragma unroll
    for (int ot = 0; ot < 2; ++ot) {
      int col = w * 32 + ot * 16 + l15;
      #pragma unroll
      for (int jj = 0; jj < 4; ++jj) {
        int g = gt * 16 + l4 * 4 + jj;
        dst[g * 256 + col] = pack_bf16x2(m1a[gt][ot][jj], m2a[gt][ot][jj]);
      }
    }
  }

  // ---------------- Tail: last-arriving block per b finalizes ----------------
  __threadfence();                     // release: partials + denoms visible
  __syncthreads();                     // all stores in this block issued
  if (t == 0) {
    uint32_t old = atomicAdd(((uint32_t*)(ws + WS_CNT)) + b, 1u);
    lastflag = (old == 7u);
  }
  __syncthreads();
  if (!lastflag) return;
  __threadfence();                     // acquire: see other blocks' partials

  // denom reduction (fixed order over the 8 chunks of this b)
  if (t < 32) {
    float s = 0.f;
    #pragma unroll
    for (int c = 0; c < 8; ++c) s += ws[WS_DN + (size_t)(b * 8 + c) * 32 + t];
    dnm[t] = s;
    out[b * G_ + t] = s * (1.0f / 1024.0f);   // weights
  }
  __syncthreads();

  // moments reduction + finalize: thread t -> g = t>>4, o = (t&15)*16 .. +15
  {
    const uint32_t* wsU = (const uint32_t*)ws;
    int g = t >> 4;
    int o0 = (t & 15) * 16;
    float inv = 1.0f / dnm[g];
    float* scales = out + 1024;
    float* locs = out + 1024 + 262144;
    #pragma unroll
    for (int q = 0; q < 4; ++q) {       // 4 x uint4 = 16 o
      int o = o0 + q * 4;
      float4 m1 = make_float4(0.f, 0.f, 0.f, 0.f);
      float4 m2 = make_float4(0.f, 0.f, 0.f, 0.f);
      #pragma unroll
      for (int c = 0; c < 8; ++c) {
        const uint32_t* p = wsU + (size_t)(b * 8 + c) * 8192 + g * 256 + o;
        uint4 v = *(const uint4*)p;
        m1.x += bflo(v.x); m1.y += bflo(v.y); m1.z += bflo(v.z); m1.w += bflo(v.w);
        m2.x += bfhi(v.x); m2.y += bfhi(v.y); m2.z += bfhi(v.z); m2.w += bfhi(v.w);
      }
      float4 lc = make_float4(m1.x * inv, m1.y * inv, m1.z * inv, m1.w * inv);
      float4 sc;
      sc.x = sqrtf(fmaxf(m2.x * inv - lc.x * lc.x, 0.f));
      sc.y = sqrtf(fmaxf(m2.y * inv - lc.y * lc.y, 0.f));
      sc.z = sqrtf(fmaxf(m2.z * inv - lc.z * lc.z, 0.f));
      sc.w = sqrtf(fmaxf(m2.w * inv - lc.w * lc.w, 0.f));
      int oi = ((b * G_ + g) << 8) + o;
      *(float4*)(scales + oi) = sc;
      *(float4*)(locs + oi) = lc;
    }
  }
}

extern "C" void kernel_launch(void* const* d_in, const int* in_sizes, int n_in,
                              void* d_out, int out_size, void* d_ws, size_t ws_size,
                              hipStream_t stream)
{
  const float* x = (const float*)d_in[0];
  const float* W = (const float*)d_in[1];
  const float* bpi = (const float*)d_in[2];
  float* out = (float*)d_out;
  float* ws = (float*)d_ws;
  hipLaunchKernelGGL(mdn_k0, dim3(8), dim3(256), 0, stream, W, ws);
  hipLaunchKernelGGL(mdn_kf, dim3(256), dim3(512), 0, stream, x, bpi, ws, out);
}

// Round 16
// 29.982 us; speedup vs baseline: 3.4192x; 3.4192x over previous
//
#include <hip/hip_runtime.h>
#include <stdint.h>

#define B_ 32
#define N_ 1024
#define D_ 512
#define G_ 32

typedef __attribute__((ext_vector_type(8))) short short8;
typedef __attribute__((ext_vector_type(4))) float f32x4;
union U4S8 { uint4 u; short8 s; };

// ws float-offsets:
//   [0, 2097152)   : partials, 256 blocks x [32 g][256 o] u32(lo=bf16 m1, hi=bf16 m2) = 8 MB
//   WS_DN (+8192)  : denom partials, 256 x 32
//   WS_WF (+8192)  : W bf16 frag-layout (2048 uint4 = 32 KB)
#define WS_DN  2097152
#define WS_WF  2105344

__device__ inline uint32_t pack_bf16x2(float a, float b) {
  uint32_t ua = __float_as_uint(a);
  uint32_t ub = __float_as_uint(b);
  ua += 0x7FFFu + ((ua >> 16) & 1u);
  ub += 0x7FFFu + ((ub >> 16) & 1u);
  return (ua >> 16) | (ub & 0xFFFF0000u);
}
__device__ inline uint16_t bf16r(float a) {
  uint32_t u = __float_as_uint(a);
  u += 0x7FFFu + ((u >> 16) & 1u);
  return (uint16_t)(u >> 16);
}
__device__ inline float bflo(uint32_t u) { return __uint_as_float(u << 16); }
__device__ inline float bfhi(uint32_t u) { return __uint_as_float(u & 0xFFFF0000u); }
__device__ inline int slot_of(int o) { return (o & 7) ^ ((o >> 3) & 3); }

// ---------------- K0: pre-pack W into bf16 MFMA frag layout -----------------
__global__ __launch_bounds__(256) void mdn_k0(
    const float* __restrict__ W, float* ws)
{
  int s = blockIdx.x * 256 + threadIdx.x;     // 0..2047
  int g = s >> 6;
  int d0 = (s & 63) * 8;
  const float4* src = (const float4*)(W + g * D_ + d0);
  float4 f0 = src[0], f1 = src[1];
  int ks = d0 >> 5, ksub = (d0 >> 3) & 3;
  uint4 v;
  v.x = pack_bf16x2(f0.x, f0.y); v.y = pack_bf16x2(f0.z, f0.w);
  v.z = pack_bf16x2(f1.x, f1.y); v.w = pack_bf16x2(f1.z, f1.w);
  ((uint4*)(ws + WS_WF))[(ks * 4 + ksub) * 32 + g] = v;
}

// ---------------- KF: single-x-pass fused kernel ----------------------------
// 256 blocks x 512 thr (8 waves x 16 rows = 128 rows), 1 block/CU.
// Phase 1: x direct-to-reg (read ONCE); logits MFMA vs prepacked W; packed
//   A-frag u32s written LINEARLY to XT[oc][r][16 oi] (one b128/k-step).
// Phase 2: moments MFMA; B-frags via ds_read_b64_tr_b16 (per-lane addr carries
//   column l15*8; tile=addr&~127, elem j = tile[col + j*16]). Partials packed
//   u32(lo=bf16 m1, hi=bf16 m2) -> halves the K3 round-trip.
__global__ __launch_bounds__(512, 2) void mdn_kf(
    const float* __restrict__ x, const float* __restrict__ bpi, float* ws)
{
  __shared__ uint32_t XT[32768];     // 128 KB: [32 oc][128 r][16 oi] bf16 linear
  __shared__ uint32_t PT[2048];      //   8 KB: piT [32 g][128 r bf16], swizzled
  __shared__ float wpart[8][32];

  const int t = threadIdx.x;
  const int bid = blockIdx.x;
  const int b = bid >> 3;
  const int n0 = (bid & 7) * 128;
  const int w = t >> 6;
  const int lane = t & 63;
  const int l15 = lane & 15, l4 = lane >> 4;

  // ---------------- Phase 1: logits + linear subtiled staging ----------------
  const float* abase =
      x + ((size_t)(b * N_ + n0 + w * 16 + l15)) * D_ + l4 * 8;
  const uint4* wf4 = (const uint4*)(ws + WS_WF);
  const int r = w * 16 + l15;        // this thread's row (0..127)

  f32x4 acc0 = {0.f, 0.f, 0.f, 0.f};
  f32x4 acc1 = {0.f, 0.f, 0.f, 0.f};

  #pragma unroll
  for (int h = 0; h < 2; ++h) {
    float4 fa[8], fb[8];
    #pragma unroll
    for (int k = 0; k < 8; ++k) {
      const float* s = abase + (h * 8 + k) * 32;
      fa[k] = *(const float4*)s; fb[k] = *(const float4*)(s + 4);
    }
    #pragma unroll
    for (int k = 0; k < 8; ++k) {
      int ks = h * 8 + k;
      U4S8 a;
      a.u.x = pack_bf16x2(fa[k].x, fa[k].y);
      a.u.y = pack_bf16x2(fa[k].z, fa[k].w);
      a.u.z = pack_bf16x2(fb[k].x, fb[k].y);
      a.u.w = pack_bf16x2(fb[k].z, fb[k].w);
      // linear subtiled store: d0 = l4*8 + ks*32; oc = d0>>4; oi = d0&15
      {
        int d0 = l4 * 8 + ks * 32;
        unsigned xtb = (unsigned)((d0 >> 4) * 4096 + r * 32 + (d0 & 15) * 2);
        *(uint4*)((char*)XT + xtb) = a.u;      // 16B aligned
      }
      // logits MFMA
      int wi = (ks * 4 + l4) * 32 + l15;
      U4S8 w0, w1;
      w0.u = wf4[wi];
      w1.u = wf4[wi + 16];
      acc0 = __builtin_amdgcn_mfma_f32_16x16x32_bf16(a.s, w0.s, acc0, 0, 0, 0);
      acc1 = __builtin_amdgcn_mfma_f32_16x16x32_bf16(a.s, w1.s, acc1, 0, 0, 0);
    }
  }

  // bias + in-register softmax (C layout: g = l15 / 16+l15; row = w*16+l4*4+j)
  float bs0 = bpi[l15], bs1 = bpi[16 + l15];
  float pi0[4], pi1[4];
  float dsum0 = 0.f, dsum1 = 0.f;
  #pragma unroll
  for (int j = 0; j < 4; ++j) {
    float v0 = acc0[j] + bs0, v1 = acc1[j] + bs1;
    float m = fmaxf(v0, v1);
    m = fmaxf(m, __shfl_xor(m, 1));
    m = fmaxf(m, __shfl_xor(m, 2));
    m = fmaxf(m, __shfl_xor(m, 4));
    m = fmaxf(m, __shfl_xor(m, 8));
    float e0 = __expf(v0 - m), e1 = __expf(v1 - m);
    float s = e0 + e1;
    s += __shfl_xor(s, 1); s += __shfl_xor(s, 2);
    s += __shfl_xor(s, 4); s += __shfl_xor(s, 8);
    float inv = 1.0f / s;
    pi0[j] = e0 * inv; pi1[j] = e1 * inv;
    dsum0 += pi0[j];   dsum1 += pi1[j];
  }
  dsum0 += __shfl_xor(dsum0, 16); dsum0 += __shfl_xor(dsum0, 32);
  dsum1 += __shfl_xor(dsum1, 16); dsum1 += __shfl_xor(dsum1, 32);
  if (lane < 16) { wpart[w][lane] = dsum0; wpart[w][16 + lane] = dsum1; }

  // piT -> LDS (u16 scatter, swizzled; only 8 per thread)
  {
    uint16_t* p16 = (uint16_t*)PT;
    int rbase = w * 16 + l4 * 4;
    int g0 = l15, g1 = 16 + l15;
    int s0 = slot_of(g0) << 3, s1 = slot_of(g1) << 3;
    #pragma unroll
    for (int j = 0; j < 4; ++j) {
      int rr = rbase + j;
      p16[g0 * 128 + (rr ^ s0)] = bf16r(pi0[j]);
      p16[g1 * 128 + (rr ^ s1)] = bf16r(pi1[j]);
    }
  }
  __syncthreads();

  if (t < 32) {
    float s = 0.f;
    #pragma unroll
    for (int ww = 0; ww < 8; ++ww) s += wpart[ww][t];
    ws[WS_DN + (size_t)bid * 32 + t] = s;
  }

  // ---------------- Phase 2: moments via HW transpose reads ----------------
  f32x4 m1a[2][2] = {{{0.f,0.f,0.f,0.f},{0.f,0.f,0.f,0.f}},
                     {{0.f,0.f,0.f,0.f},{0.f,0.f,0.f,0.f}}};
  f32x4 m2a[2][2] = {{{0.f,0.f,0.f,0.f},{0.f,0.f,0.f,0.f}},
                     {{0.f,0.f,0.f,0.f},{0.f,0.f,0.f,0.f}}};
  const int gA0 = l15, gA1 = 16 + l15;
  const int sA0 = slot_of(gA0) << 2, sA1 = slot_of(gA1) << 2;
  const unsigned xtb0 = (unsigned)(uintptr_t)XT;

  #pragma unroll
  for (int ksi = 0; ksi < 4; ++ksi) {
    int rofs = ksi * 16 + l4 * 4;            // u32 offset within a PT row
    U4S8 a0, a1;
    a0.u = *(const uint4*)(PT + gA0 * 64 + (rofs ^ sA0));
    a1.u = *(const uint4*)(PT + gA1 * 64 + (rofs ^ sA1));
    // per-lane tr_read addr: tile (rows ksi*32+l4*8 ..+3) + column l15
    const unsigned rowb = (unsigned)(ksi * 1024 + l4 * 256 + l15 * 8);
    #pragma unroll
    for (int ot = 0; ot < 2; ++ot) {
      unsigned am = xtb0 + (unsigned)((w * 2 + ot) * 4096) + rowb;
      unsigned as = am + 16 * 4096;
      uint64_t q0, q1, q2, q3;
      asm volatile("ds_read_b64_tr_b16 %0, %1" : "=v"(q0) : "v"(am));
      asm volatile("ds_read_b64_tr_b16 %0, %1 offset:128" : "=v"(q1) : "v"(am));
      asm volatile("ds_read_b64_tr_b16 %0, %1" : "=v"(q2) : "v"(as));
      asm volatile("ds_read_b64_tr_b16 %0, %1 offset:128" : "=v"(q3) : "v"(as));
      asm volatile("s_waitcnt lgkmcnt(0)" ::: "memory");
      __builtin_amdgcn_sched_barrier(0);
      U4S8 Bm, Bs;
      Bm.u.x = (uint32_t)q0; Bm.u.y = (uint32_t)(q0 >> 32);
      Bm.u.z = (uint32_t)q1; Bm.u.w = (uint32_t)(q1 >> 32);
      Bs.u.x = (uint32_t)q2; Bs.u.y = (uint32_t)(q2 >> 32);
      Bs.u.z = (uint32_t)q3; Bs.u.w = (uint32_t)(q3 >> 32);
      uint32_t bm[4] = {Bm.u.x, Bm.u.y, Bm.u.z, Bm.u.w};
      uint32_t sw[4] = {Bs.u.x, Bs.u.y, Bs.u.z, Bs.u.w};
      U4S8 B2;
      uint32_t b2w[4];
      #pragma unroll
      for (int i = 0; i < 4; ++i) {
        float lo = bflo(bm[i]) * bflo(bm[i]) + bflo(sw[i]) * bflo(sw[i]);
        float hi = bfhi(bm[i]) * bfhi(bm[i]) + bfhi(sw[i]) * bfhi(sw[i]);
        b2w[i] = pack_bf16x2(lo, hi);
      }
      B2.u.x = b2w[0]; B2.u.y = b2w[1]; B2.u.z = b2w[2]; B2.u.w = b2w[3];
      m1a[0][ot] = __builtin_amdgcn_mfma_f32_16x16x32_bf16(a0.s, Bm.s, m1a[0][ot], 0, 0, 0);
      m1a[1][ot] = __builtin_amdgcn_mfma_f32_16x16x32_bf16(a1.s, Bm.s, m1a[1][ot], 0, 0, 0);
      m2a[0][ot] = __builtin_amdgcn_mfma_f32_16x16x32_bf16(a0.s, B2.s, m2a[0][ot], 0, 0, 0);
      m2a[1][ot] = __builtin_amdgcn_mfma_f32_16x16x32_bf16(a1.s, B2.s, m2a[1][ot], 0, 0, 0);
    }
  }

  // partial store: [32 g][256 o] u32 (lo = bf16 m1, hi = bf16 m2)
  uint32_t* dst = (uint32_t*)ws + (size_t)bid * 8192;
  #pragma unroll
  for (int gt = 0; gt < 2; ++gt) {
    #pragma unroll
    for (int ot = 0; ot < 2; ++ot) {
      int col = w * 32 + ot * 16 + l15;
      #pragma unroll
      for (int jj = 0; jj < 4; ++jj) {
        int g = gt * 16 + l4 * 4 + jj;
        dst[g * 256 + col] = pack_bf16x2(m1a[gt][ot][jj], m2a[gt][ot][jj]);
      }
    }
  }
}

// ---------------- K3: reduce 8 row-chunk partials + finalize ----------------
__global__ __launch_bounds__(256) void mdn_k3(
    const float* __restrict__ ws, float* __restrict__ out)
{
  __shared__ float dnm[G_];
  const int blk = blockIdx.x;
  const int b = blk >> 3, oc = blk & 7;   // oc: 32-wide o chunk
  const int t = threadIdx.x;
  if (t < G_) {
    float s = 0.f;
    #pragma unroll
    for (int c = 0; c < 8; ++c) s += ws[WS_DN + (size_t)(b * 8 + c) * 32 + t];
    dnm[t] = s;
    if (oc == 0) out[b * G_ + t] = s * (1.0f / 1024.0f);   // weights
  }
  __syncthreads();
  const int g = t >> 3;
  const int o = oc * 32 + (t & 7) * 4;
  const uint32_t* wsU = (const uint32_t*)ws;
  float4 m1 = make_float4(0.f, 0.f, 0.f, 0.f);
  float4 m2 = make_float4(0.f, 0.f, 0.f, 0.f);
  #pragma unroll
  for (int c = 0; c < 8; ++c) {
    const uint32_t* p = wsU + (size_t)(b * 8 + c) * 8192 + g * 256 + o;
    uint4 v = *(const uint4*)p;
    m1.x += bflo(v.x); m1.y += bflo(v.y); m1.z += bflo(v.z); m1.w += bflo(v.w);
    m2.x += bfhi(v.x); m2.y += bfhi(v.y); m2.z += bfhi(v.z); m2.w += bfhi(v.w);
  }
  float inv = 1.0f / dnm[g];
  float4 lc = make_float4(m1.x * inv, m1.y * inv, m1.z * inv, m1.w * inv);
  float4 sc;
  sc.x = sqrtf(fmaxf(m2.x * inv - lc.x * lc.x, 0.f));
  sc.y = sqrtf(fmaxf(m2.y * inv - lc.y * lc.y, 0.f));
  sc.z = sqrtf(fmaxf(m2.z * inv - lc.z * lc.z, 0.f));
  sc.w = sqrtf(fmaxf(m2.w * inv - lc.w * lc.w, 0.f));
  float* scales = out + 1024;
  float* locs = out + 1024 + 262144;
  int oi = ((b * G_ + g) << 8) + o;
  *(float4*)(scales + oi) = sc;
  *(float4*)(locs + oi) = lc;
}

extern "C" void kernel_launch(void* const* d_in, const int* in_sizes, int n_in,
                              void* d_out, int out_size, void* d_ws, size_t ws_size,
                              hipStream_t stream)
{
  const float* x = (const float*)d_in[0];
  const float* W = (const float*)d_in[1];
  const float* bpi = (const float*)d_in[2];
  float* out = (float*)d_out;
  float* ws = (float*)d_ws;
  hipLaunchKernelGGL(mdn_k0, dim3(8), dim3(256), 0, stream, W, ws);
  hipLaunchKernelGGL(mdn_kf, dim3(256), dim3(512), 0, stream, x, bpi, ws);
  hipLaunchKernelGGL(mdn_k3, dim3(256), dim3(256), 0, stream, ws, out);
}